// Round 1
// baseline (586.978 us; speedup 1.0000x reference)
//
#include <hip/hip_runtime.h>

// ---- ordered-uint encoding for float atomicMax (monotone bijection) ----
__device__ __forceinline__ unsigned ford(float f) {
    unsigned u = __float_as_uint(f);
    return (u & 0x80000000u) ? ~u : (u | 0x80000000u);
}
__device__ __forceinline__ float funord(unsigned u) {
    return (u & 0x80000000u) ? __uint_as_float(u & 0x7fffffffu) : __uint_as_float(~u);
}

__global__ void k_init(float* __restrict__ out, const float* __restrict__ bias,
                       unsigned* __restrict__ smaxu, float* __restrict__ den, int N) {
    int idx = blockIdx.x * blockDim.x + threadIdx.x;
    if (idx < 2 * N) { smaxu[idx] = 0u; den[idx] = 0.f; }
    if (idx < N * 32) out[idx] = bias[idx & 31];
}

__global__ void k_score(const float* __restrict__ feat, const int* __restrict__ src,
                        const int* __restrict__ dst, const int* __restrict__ etype,
                        const float* __restrict__ attn_w, const float* __restrict__ attn_b,
                        float* __restrict__ score, unsigned* __restrict__ smaxu,
                        int E, int N) {
    int e = blockIdx.x * blockDim.x + threadIdx.x;
    if (e >= E) return;
    int s = src[e], d = dst[e], r = etype[e];
    const float4* zs = (const float4*)(feat + (long)s * 32);
    const float4* zd = (const float4*)(feat + (long)d * 32);
    const float4* aw = (const float4*)attn_w;
    float acc = attn_b[0];
    #pragma unroll
    for (int j = 0; j < 8; ++j) {
        float4 a = zs[j], w = aw[j];
        acc = fmaf(a.x, w.x, acc); acc = fmaf(a.y, w.y, acc);
        acc = fmaf(a.z, w.z, acc); acc = fmaf(a.w, w.w, acc);
    }
    #pragma unroll
    for (int j = 0; j < 8; ++j) {
        float4 a = zd[j], w = aw[8 + j];
        acc = fmaf(a.x, w.x, acc); acc = fmaf(a.y, w.y, acc);
        acc = fmaf(a.z, w.z, acc); acc = fmaf(a.w, w.w, acc);
    }
    float sc = acc >= 0.f ? acc : 0.01f * acc;  // leaky_relu(0.01)
    score[e] = sc;
    atomicMax(&smaxu[r * N + d], ford(sc));
}

__global__ void k_expden(const int* __restrict__ dst, const int* __restrict__ etype,
                         const float* __restrict__ score, const unsigned* __restrict__ smaxu,
                         float* __restrict__ ex, float* __restrict__ den, int E, int N) {
    int e = blockIdx.x * blockDim.x + threadIdx.x;
    if (e >= E) return;
    int d = dst[e], r = etype[e];
    float m = funord(smaxu[r * N + d]);
    float v = expf(score[e] - m);
    ex[e] = v;
    atomicAdd(&den[r * N + d], v);
}

// One thread per edge. W rows are wave-uniform (<=2 distinct pointers per wave)
// -> broadcast loads served by L1. msg[o] = sum_{f,i} u[f]*z[i]*W[f*32+i][o] + bias-rows.
__global__ __launch_bounds__(256) void k_msg(
    const float* __restrict__ feat, const float* __restrict__ efeat,
    const int* __restrict__ src, const int* __restrict__ dst, const int* __restrict__ etype,
    const float* __restrict__ w1, const float* __restrict__ b1,
    const float* __restrict__ w2, const float* __restrict__ b2,
    const float* __restrict__ ex, const float* __restrict__ den,
    float* __restrict__ out, int E, int N) {
    int e = blockIdx.x * blockDim.x + threadIdx.x;
    if (e >= E) return;
    int s = src[e], d = dst[e], r = etype[e];
    const float* W = r ? w2 : w1;
    const float* B = r ? b2 : b1;

    float z[32];
    const float4* zp = (const float4*)(feat + (long)s * 32);
    #pragma unroll
    for (int j = 0; j < 8; ++j) {
        float4 v = zp[j];
        z[4 * j + 0] = v.x; z[4 * j + 1] = v.y; z[4 * j + 2] = v.z; z[4 * j + 3] = v.w;
    }

    float msg[32];
    #pragma unroll
    for (int o = 0; o < 32; ++o) msg[o] = 0.f;

    const float* uptr = efeat + (long)e * 16;
    #pragma unroll 1
    for (int f = 0; f < 16; ++f) {
        float uf = uptr[f];
        const float* rowb = W + f * 1024;
        #pragma unroll
        for (int i = 0; i < 32; ++i) {
            float p = uf * z[i];
            const float4* row = (const float4*)(rowb + i * 32);
            #pragma unroll
            for (int q = 0; q < 8; ++q) {
                float4 wv = row[q];
                msg[4 * q + 0] = fmaf(p, wv.x, msg[4 * q + 0]);
                msg[4 * q + 1] = fmaf(p, wv.y, msg[4 * q + 1]);
                msg[4 * q + 2] = fmaf(p, wv.z, msg[4 * q + 2]);
                msg[4 * q + 3] = fmaf(p, wv.w, msg[4 * q + 3]);
            }
        }
    }
    // bias rows: msg[o] += sum_i z[i] * B[i*32+o]
    #pragma unroll 1
    for (int i = 0; i < 32; ++i) {
        float p = z[i];
        const float4* row = (const float4*)(B + i * 32);
        #pragma unroll
        for (int q = 0; q < 8; ++q) {
            float4 wv = row[q];
            msg[4 * q + 0] = fmaf(p, wv.x, msg[4 * q + 0]);
            msg[4 * q + 1] = fmaf(p, wv.y, msg[4 * q + 1]);
            msg[4 * q + 2] = fmaf(p, wv.z, msg[4 * q + 2]);
            msg[4 * q + 3] = fmaf(p, wv.w, msg[4 * q + 3]);
        }
    }

    float alpha = ex[e] / den[r * N + d];
    float* op = out + (long)d * 32;
    #pragma unroll
    for (int o = 0; o < 32; ++o) atomicAdd(op + o, alpha * msg[o]);
}

extern "C" void kernel_launch(void* const* d_in, const int* in_sizes, int n_in,
                              void* d_out, int out_size, void* d_ws, size_t ws_size,
                              hipStream_t stream) {
    const float* feat   = (const float*)d_in[0];
    const float* efeat  = (const float*)d_in[1];
    const int*   src    = (const int*)d_in[2];
    const int*   dst    = (const int*)d_in[3];
    const int*   etype  = (const int*)d_in[4];
    const float* attn_w = (const float*)d_in[5];
    const float* attn_b = (const float*)d_in[6];
    const float* ef1_w  = (const float*)d_in[7];
    const float* ef1_b  = (const float*)d_in[8];
    const float* ef2_w  = (const float*)d_in[9];
    const float* ef2_b  = (const float*)d_in[10];
    const float* bias   = (const float*)d_in[11];

    int E = in_sizes[2];
    int N = in_sizes[0] / 32;

    float*    score = (float*)d_ws;
    float*    ex    = score + E;
    unsigned* smaxu = (unsigned*)(ex + E);
    float*    den   = (float*)(smaxu + 2 * N);
    float*    out   = (float*)d_out;

    int initTotal = N * 32;
    k_init<<<(initTotal + 255) / 256, 256, 0, stream>>>(out, bias, smaxu, den, N);
    k_score<<<(E + 255) / 256, 256, 0, stream>>>(feat, src, dst, etype, attn_w, attn_b,
                                                 score, smaxu, E, N);
    k_expden<<<(E + 255) / 256, 256, 0, stream>>>(dst, etype, score, smaxu, ex, den, E, N);
    k_msg<<<(E + 255) / 256, 256, 0, stream>>>(feat, efeat, src, dst, etype,
                                               ef1_w, ef1_b, ef2_w, ef2_b,
                                               ex, den, out, E, N);
}

// Round 2
// 150.598 us; speedup vs baseline: 3.8977x; 3.8977x over previous
//
#include <hip/hip_runtime.h>

// ---- ordered-uint encoding for float atomicMax (monotone bijection) ----
__device__ __forceinline__ unsigned ford(float f) {
    unsigned u = __float_as_uint(f);
    return (u & 0x80000000u) ? ~u : (u | 0x80000000u);
}
__device__ __forceinline__ float funord(unsigned u) {
    return (u & 0x80000000u) ? __uint_as_float(u & 0x7fffffffu) : __uint_as_float(~u);
}

__global__ void k_init(float* __restrict__ out, const float* __restrict__ bias,
                       unsigned* __restrict__ smaxu, float* __restrict__ den,
                       int* __restrict__ cnt, int N) {
    int idx = blockIdx.x * blockDim.x + threadIdx.x;
    if (idx < 2) cnt[idx] = 0;
    if (idx < 2 * N) { smaxu[idx] = 0u; den[idx] = 0.f; }
    if (idx < N * 32) out[idx] = bias[idx & 31];
}

__global__ void k_score(const float* __restrict__ feat, const int* __restrict__ src,
                        const int* __restrict__ dst, const int* __restrict__ etype,
                        const float* __restrict__ attn_w, const float* __restrict__ attn_b,
                        float* __restrict__ score, unsigned* __restrict__ smaxu,
                        int E, int N) {
    int e = blockIdx.x * blockDim.x + threadIdx.x;
    if (e >= E) return;
    int s = src[e], d = dst[e], r = etype[e];
    const float4* zs = (const float4*)(feat + (long)s * 32);
    const float4* zd = (const float4*)(feat + (long)d * 32);
    const float4* aw = (const float4*)attn_w;
    float acc = attn_b[0];
    #pragma unroll
    for (int j = 0; j < 8; ++j) {
        float4 a = zs[j], w = aw[j];
        acc = fmaf(a.x, w.x, acc); acc = fmaf(a.y, w.y, acc);
        acc = fmaf(a.z, w.z, acc); acc = fmaf(a.w, w.w, acc);
    }
    #pragma unroll
    for (int j = 0; j < 8; ++j) {
        float4 a = zd[j], w = aw[8 + j];
        acc = fmaf(a.x, w.x, acc); acc = fmaf(a.y, w.y, acc);
        acc = fmaf(a.z, w.z, acc); acc = fmaf(a.w, w.w, acc);
    }
    float sc = acc >= 0.f ? acc : 0.01f * acc;  // leaky_relu(0.01)
    score[e] = sc;
    atomicMax(&smaxu[r * N + d], ford(sc));
}

// exp + denominator atomics, fused with relation partition (ballot + atomic append).
__global__ void k_mid(const int* __restrict__ dst, const int* __restrict__ etype,
                      const float* __restrict__ score, const unsigned* __restrict__ smaxu,
                      float* __restrict__ ex, float* __restrict__ den,
                      int* __restrict__ perm0, int* __restrict__ perm1,
                      int* __restrict__ cnt, int E, int N) {
    int e = blockIdx.x * blockDim.x + threadIdx.x;
    bool valid = e < E;
    int d = 0, r = 0;
    if (valid) {
        d = dst[e]; r = etype[e];
        float m = funord(smaxu[r * N + d]);
        float v = expf(score[e] - m);
        ex[e] = v;
        atomicAdd(&den[r * N + d], v);
    }
    unsigned long long b1 = __ballot(valid && (r == 1));
    unsigned long long b0 = __ballot(valid && (r == 0));
    int lane = threadIdx.x & 63;
    int base0 = 0, base1 = 0;
    if (lane == 0) {
        if (b0) base0 = atomicAdd(&cnt[0], (int)__popcll(b0));
        if (b1) base1 = atomicAdd(&cnt[1], (int)__popcll(b1));
    }
    base0 = __shfl(base0, 0);
    base1 = __shfl(base1, 0);
    unsigned long long lt = (1ull << lane) - 1ull;
    if (valid) {
        if (r) perm1[base1 + (int)__popcll(b1 & lt)] = e;
        else   perm0[base0 + (int)__popcll(b0 & lt)] = e;
    }
}

// Message + scatter. Block = 256 threads: 8 o-lanes (float4 each) x 32 edge-slots,
// 4 sequential edges/thread -> 128 edges per block, single relation per block.
// z,u staged in LDS (pad 36/20 dwords: conflict-free b128/b32 reads).
__global__ __launch_bounds__(256) void k_msg(
    const float* __restrict__ feat, const float* __restrict__ efeat,
    const int* __restrict__ src, const int* __restrict__ dst,
    const float* __restrict__ w1p, const float* __restrict__ b1p,
    const float* __restrict__ w2p, const float* __restrict__ b2p,
    const float* __restrict__ ex, const float* __restrict__ den,
    const int* __restrict__ perm0, const int* __restrict__ perm1,
    const int* __restrict__ cnt, float* __restrict__ out, int N) {
    int r = blockIdx.y;
    int count = cnt[r];
    int base = blockIdx.x * 128;
    if (base >= count) return;
    const int*   perm = r ? perm1 : perm0;
    const float* W    = r ? w2p : w1p;
    const float* B    = r ? b2p : b1p;

    __shared__ float z_lds[128][36];
    __shared__ float u_lds[128][20];

    {   // stage z (32 f) and u (16 f) for the block's 128 edges
        int row = threadIdx.x >> 1, half = threadIdx.x & 1;
        int gi = base + row;
        int e = perm[min(gi, count - 1)];
        int s = src[e];
        const float4* zp = (const float4*)(feat + (long)s * 32 + half * 16);
        float4 a0 = zp[0], a1 = zp[1], a2 = zp[2], a3 = zp[3];
        const float4* up = (const float4*)(efeat + (long)e * 16 + half * 8);
        float4 c0 = up[0], c1 = up[1];
        float* zd = &z_lds[row][half * 16];
        *(float4*)(zd + 0) = a0; *(float4*)(zd + 4) = a1;
        *(float4*)(zd + 8) = a2; *(float4*)(zd + 12) = a3;
        float* ud = &u_lds[row][half * 8];
        *(float4*)(ud + 0) = c0; *(float4*)(ud + 4) = c1;
    }
    __syncthreads();

    int slot = threadIdx.x >> 3, ol = threadIdx.x & 7;
    int li[4], dj[4]; float al[4];
    #pragma unroll
    for (int j = 0; j < 4; ++j) {
        li[j] = j * 32 + slot;
        int gi = base + li[j];
        bool v = gi < count;
        int e = perm[min(gi, count - 1)];
        dj[j] = dst[e];
        al[j] = v ? ex[e] / den[r * N + dj[j]] : 0.f;
    }

    float msg[4][4];
    #pragma unroll
    for (int j = 0; j < 4; ++j) { msg[j][0] = 0; msg[j][1] = 0; msg[j][2] = 0; msg[j][3] = 0; }

    for (int f = 0; f < 17; ++f) {   // f==16 is the bias row (u=1, rows=B)
        const float* Wf = (f < 16) ? (W + f * 1024) : B;
        float u0, u1, u2, u3;
        if (f < 16) {
            u0 = u_lds[li[0]][f]; u1 = u_lds[li[1]][f];
            u2 = u_lds[li[2]][f]; u3 = u_lds[li[3]][f];
        } else { u0 = u1 = u2 = u3 = 1.f; }
        #pragma unroll 2
        for (int ic = 0; ic < 8; ++ic) {
            const float* wb = Wf + ic * 128 + ol * 4;
            float4 wv0 = *(const float4*)(wb);
            float4 wv1 = *(const float4*)(wb + 32);
            float4 wv2 = *(const float4*)(wb + 64);
            float4 wv3 = *(const float4*)(wb + 96);
            float4 z0 = *(const float4*)&z_lds[li[0]][ic * 4];
            float4 z1 = *(const float4*)&z_lds[li[1]][ic * 4];
            float4 z2 = *(const float4*)&z_lds[li[2]][ic * 4];
            float4 z3 = *(const float4*)&z_lds[li[3]][ic * 4];
            #define ACC(WV, CX) \
            { float p0 = u0 * z0.CX, p1 = u1 * z1.CX, p2 = u2 * z2.CX, p3 = u3 * z3.CX; \
              msg[0][0] = fmaf(p0, WV.x, msg[0][0]); msg[0][1] = fmaf(p0, WV.y, msg[0][1]); \
              msg[0][2] = fmaf(p0, WV.z, msg[0][2]); msg[0][3] = fmaf(p0, WV.w, msg[0][3]); \
              msg[1][0] = fmaf(p1, WV.x, msg[1][0]); msg[1][1] = fmaf(p1, WV.y, msg[1][1]); \
              msg[1][2] = fmaf(p1, WV.z, msg[1][2]); msg[1][3] = fmaf(p1, WV.w, msg[1][3]); \
              msg[2][0] = fmaf(p2, WV.x, msg[2][0]); msg[2][1] = fmaf(p2, WV.y, msg[2][1]); \
              msg[2][2] = fmaf(p2, WV.z, msg[2][2]); msg[2][3] = fmaf(p2, WV.w, msg[2][3]); \
              msg[3][0] = fmaf(p3, WV.x, msg[3][0]); msg[3][1] = fmaf(p3, WV.y, msg[3][1]); \
              msg[3][2] = fmaf(p3, WV.z, msg[3][2]); msg[3][3] = fmaf(p3, WV.w, msg[3][3]); }
            ACC(wv0, x) ACC(wv1, y) ACC(wv2, z) ACC(wv3, w)
            #undef ACC
        }
    }

    #pragma unroll
    for (int j = 0; j < 4; ++j) {
        float a = al[j];
        float* op = out + (long)dj[j] * 32 + ol * 4;
        atomicAdd(op + 0, a * msg[j][0]);
        atomicAdd(op + 1, a * msg[j][1]);
        atomicAdd(op + 2, a * msg[j][2]);
        atomicAdd(op + 3, a * msg[j][3]);
    }
}

extern "C" void kernel_launch(void* const* d_in, const int* in_sizes, int n_in,
                              void* d_out, int out_size, void* d_ws, size_t ws_size,
                              hipStream_t stream) {
    const float* feat   = (const float*)d_in[0];
    const float* efeat  = (const float*)d_in[1];
    const int*   src    = (const int*)d_in[2];
    const int*   dst    = (const int*)d_in[3];
    const int*   etype  = (const int*)d_in[4];
    const float* attn_w = (const float*)d_in[5];
    const float* attn_b = (const float*)d_in[6];
    const float* ef1_w  = (const float*)d_in[7];
    const float* ef1_b  = (const float*)d_in[8];
    const float* ef2_w  = (const float*)d_in[9];
    const float* ef2_b  = (const float*)d_in[10];
    const float* bias   = (const float*)d_in[11];

    int E = in_sizes[2];
    int N = in_sizes[0] / 32;

    float*    score = (float*)d_ws;
    float*    ex    = score + E;
    unsigned* smaxu = (unsigned*)(ex + E);
    float*    den   = (float*)(smaxu + 2 * N);
    int*      cnt   = (int*)(den + 2 * N);
    int*      perm0 = cnt + 2;
    int*      perm1 = perm0 + E;
    float*    out   = (float*)d_out;

    int initTotal = N * 32;
    k_init<<<(initTotal + 255) / 256, 256, 0, stream>>>(out, bias, smaxu, den, cnt, N);
    k_score<<<(E + 255) / 256, 256, 0, stream>>>(feat, src, dst, etype, attn_w, attn_b,
                                                 score, smaxu, E, N);
    k_mid<<<(E + 255) / 256, 256, 0, stream>>>(dst, etype, score, smaxu, ex, den,
                                               perm0, perm1, cnt, E, N);
    dim3 mgrid((E + 127) / 128, 2);
    k_msg<<<mgrid, 256, 0, stream>>>(feat, efeat, src, dst,
                                     ef1_w, ef1_b, ef2_w, ef2_b,
                                     ex, den, perm0, perm1, cnt, out, N);
}